// Round 1
// baseline (596.588 us; speedup 1.0000x reference)
//
#include <hip/hip_runtime.h>

#define H 512
#define NNODES 10000
#define NEDGES 160000
#define NLAYERS 5

typedef __attribute__((ext_vector_type(8))) short short8;
typedef __attribute__((ext_vector_type(4))) float floatx4;

// ---------- helpers ----------
__device__ inline unsigned short f2bf(float v) {
    union { float f; unsigned int u; } x; x.f = v;
    unsigned int r = (x.u + 0x7fffu + ((x.u >> 16) & 1u)) >> 16;
    return (unsigned short)r;
}
__device__ inline float bf2f(unsigned short u) {
    union { unsigned int u; float f; } x; x.u = ((unsigned int)u) << 16; return x.f;
}
__device__ inline void gl_lds16(const void* g, void* l) {
    __builtin_amdgcn_global_load_lds((const __attribute__((address_space(1))) void*)g,
                                     (__attribute__((address_space(3))) void*)l, 16, 0, 0);
}

// ---------- prep kernels ----------
__global__ void zero_int(int* __restrict__ p, int n) {
    int i = blockIdx.x * blockDim.x + threadIdx.x;
    if (i < n) p[i] = 0;
}

__global__ void cvt_f32_bf16(const float* __restrict__ in, unsigned short* __restrict__ out, int n4) {
    int i = blockIdx.x * blockDim.x + threadIdx.x;
    if (i < n4) {
        float4 v = ((const float4*)in)[i];
        ushort4 o;
        o.x = f2bf(v.x); o.y = f2bf(v.y); o.z = f2bf(v.z); o.w = f2bf(v.w);
        ((ushort4*)out)[i] = o;
    }
}

// in: [512][512] fp32 (K-major), out: [512][512] bf16 with out[n][k] = in[k][n]
__global__ void transpose_cvt(const float* __restrict__ in, unsigned short* __restrict__ out) {
    __shared__ float tile[32][33];
    const int bx = blockIdx.x * 32;  // n base
    const int by = blockIdx.y * 32;  // k base
    const int tx = threadIdx.x, ty = threadIdx.y;  // (32,8)
    for (int i = ty; i < 32; i += 8)
        tile[i][tx] = in[(size_t)(by + i) * H + bx + tx];
    __syncthreads();
    for (int i = ty; i < 32; i += 8)
        out[(size_t)(bx + i) * H + by + tx] = f2bf(tile[tx][i]);
}

__global__ void edge_hist(const int* __restrict__ rows, int* __restrict__ counts, int n) {
    int i = blockIdx.x * blockDim.x + threadIdx.x;
    if (i < n) atomicAdd(&counts[rows[i]], 1);
}

__global__ __launch_bounds__(1024)
void scan_rows(const int* __restrict__ counts, int* __restrict__ row_ptr, int n) {
    __shared__ int sums[1024];
    const int t = threadIdx.x;
    const int base = t * 16;
    int local[16];
    int s = 0;
#pragma unroll
    for (int i = 0; i < 16; ++i) {
        int idx = base + i;
        int v = (idx < n) ? counts[idx] : 0;
        local[i] = s;
        s += v;
    }
    sums[t] = s;
    __syncthreads();
    for (int off = 1; off < 1024; off <<= 1) {
        int v = (t >= off) ? sums[t - off] : 0;
        __syncthreads();
        sums[t] += v;
        __syncthreads();
    }
    const int prefix = (t == 0) ? 0 : sums[t - 1];
#pragma unroll
    for (int i = 0; i < 16; ++i) {
        int idx = base + i;
        if (idx < n) row_ptr[idx] = prefix + local[i];
    }
    if (t == 0) row_ptr[n] = sums[1023];
}

__global__ void edge_scatter(const int* __restrict__ rows, const int* __restrict__ colsin,
                             const float* __restrict__ valsin, const int* __restrict__ row_ptr,
                             int* __restrict__ fill, int* __restrict__ colsout,
                             float* __restrict__ valsout, int n) {
    int i = blockIdx.x * blockDim.x + threadIdx.x;
    if (i < n) {
        int r = rows[i];
        int pos = row_ptr[r] + atomicAdd(&fill[r], 1);
        colsout[pos] = colsin[i];
        valsout[pos] = valsin[i];
    }
}

// ---------- GEMM: C[M,N](bf16) = A[M,K](bf16) * Bt[N,K](bf16)^T, opt bias+relu ----------
// m97 structure: 128x128 tile, BK=32, 4 waves (2x2), 4x4 16x16x32 MFMA per wave.
__global__ __launch_bounds__(256)
void gemm_bf16_bt(const unsigned short* __restrict__ A, const unsigned short* __restrict__ Bt,
                  unsigned short* __restrict__ C, const float* __restrict__ bias,
                  int has_bias_relu, int M, int N, int K) {
    __shared__ __align__(16) unsigned short lsA[128 * 32];
    __shared__ __align__(16) unsigned short lsB[128 * 32];
    const int t = threadIdx.x;
    const int lane = t & 63;
    const int wave = t >> 6;
    const int wm = wave >> 1, wn = wave & 1;
    const int tileM = blockIdx.x * 128;
    const int tileN = blockIdx.y * 128;
    const int quad = lane >> 4, r16 = lane & 15;

    floatx4 acc[4][4] = {};

    // staging: 512 chunks of 16B per tile; thread handles chunks t and t+256
    const int c0 = t, c1 = t + 256;
    const int arow0 = c0 >> 2, akc0 = c0 & 3;
    const int arow1 = c1 >> 2, akc1 = c1 & 3;
    int agr0 = tileM + arow0; if (agr0 >= M) agr0 = M - 1;
    int agr1 = tileM + arow1; if (agr1 >= M) agr1 = M - 1;
    const int bgr0 = tileN + arow0;
    const int bgr1 = tileN + arow1;

    for (int k0 = 0; k0 < K; k0 += 32) {
        gl_lds16(A + (size_t)agr0 * K + k0 + akc0 * 8, lsA + c0 * 8);
        gl_lds16(A + (size_t)agr1 * K + k0 + akc1 * 8, lsA + c1 * 8);
        gl_lds16(Bt + (size_t)bgr0 * K + k0 + akc0 * 8, lsB + c0 * 8);
        gl_lds16(Bt + (size_t)bgr1 * K + k0 + akc1 * 8, lsB + c1 * 8);
        __syncthreads();  // compiler emits s_waitcnt vmcnt(0) before barrier

        short8 af[4], bf[4];
#pragma unroll
        for (int i = 0; i < 4; ++i)
            af[i] = *(const short8*)&lsA[(wm * 64 + i * 16 + r16) * 32 + quad * 8];
#pragma unroll
        for (int j = 0; j < 4; ++j)
            bf[j] = *(const short8*)&lsB[(wn * 64 + j * 16 + r16) * 32 + quad * 8];
#pragma unroll
        for (int i = 0; i < 4; ++i)
#pragma unroll
            for (int j = 0; j < 4; ++j)
                acc[i][j] = __builtin_amdgcn_mfma_f32_16x16x32_bf16(af[i], bf[j], acc[i][j], 0, 0, 0);
        __syncthreads();
    }

    // epilogue: C/D map col=lane&15, row=(lane>>4)*4+reg
#pragma unroll
    for (int i = 0; i < 4; ++i) {
#pragma unroll
        for (int j = 0; j < 4; ++j) {
            const int col = tileN + wn * 64 + j * 16 + r16;
#pragma unroll
            for (int reg = 0; reg < 4; ++reg) {
                const int row = tileM + wm * 64 + i * 16 + quad * 4 + reg;
                if (row < M) {
                    float v = acc[i][j][reg];
                    if (has_bias_relu) { v += bias[col]; v = fmaxf(v, 0.f); }
                    C[(size_t)row * N + col] = f2bf(v);
                }
            }
        }
    }
}

// ---------- SpMM + bias + relu: xout[r,:] = relu(sum_e val[e]*h[col[e],:] + bias) ----------
__global__ __launch_bounds__(512)
void spmm_bias_relu(const int* __restrict__ row_ptr, const int* __restrict__ cols,
                    const float* __restrict__ vals, const unsigned short* __restrict__ hmat,
                    const float* __restrict__ bias, unsigned short* __restrict__ xout) {
    const int r = blockIdx.x;
    const int c = threadIdx.x;
    const int s = row_ptr[r], e = row_ptr[r + 1];
    float acc = 0.f;
    for (int i = s; i < e; ++i) {
        acc += vals[i] * bf2f(hmat[(size_t)cols[i] * H + c]);
    }
    acc += bias[c];
    xout[(size_t)r * H + c] = f2bf(fmaxf(acc, 0.f));
}

// ---------- head: out[r] = sigmoid(dot(h2[r,:], w2) + b2) ----------
__global__ __launch_bounds__(256)
void final_head(const unsigned short* __restrict__ h2, const float* __restrict__ w2,
                const float* __restrict__ b2, float* __restrict__ out, int n) {
    const int wave = threadIdx.x >> 6, lane = threadIdx.x & 63;
    const int r = blockIdx.x * 4 + wave;
    if (r >= n) return;
    const unsigned short* hrow = h2 + (size_t)r * H;
    float acc = 0.f;
#pragma unroll
    for (int i = 0; i < 8; ++i) {
        const int c = lane * 8 + i;
        acc += bf2f(hrow[c]) * w2[c];
    }
#pragma unroll
    for (int off = 32; off >= 1; off >>= 1) acc += __shfl_xor(acc, off, 64);
    if (lane == 0) out[r] = 1.f / (1.f + expf(-(acc + b2[0])));
}

extern "C" void kernel_launch(void* const* d_in, const int* in_sizes, int n_in,
                              void* d_out, int out_size, void* d_ws, size_t ws_size,
                              hipStream_t stream) {
    (void)in_sizes; (void)n_in; (void)out_size; (void)ws_size;
    const float* feat   = (const float*)d_in[0];
    const int* adj_row  = (const int*)d_in[1];
    const int* adj_col  = (const int*)d_in[2];
    const float* adj_val= (const float*)d_in[3];
    const float* Wg     = (const float*)d_in[4];
    const float* bg     = (const float*)d_in[5];
    const float* vw1    = (const float*)d_in[6];
    const float* vb1    = (const float*)d_in[7];
    const float* vw2    = (const float*)d_in[8];
    const float* vb2    = (const float*)d_in[9];
    float* out = (float*)d_out;

    // workspace layout (bytes)
    char* ws = (char*)d_ws;
    unsigned short* x  = (unsigned short*)(ws + 0);          // 10000*512 bf16 = 10,240,000
    unsigned short* h  = (unsigned short*)(ws + 10240000);   // 10,240,000
    unsigned short* Wt = (unsigned short*)(ws + 20480000);   // 6*512*512 bf16 = 3,145,728
    int*   row_ptr = (int*)(ws + 23625728);                  // 40,960
    int*   counts  = (int*)(ws + 23666688);                  // 40,960
    int*   fill    = (int*)(ws + 23707648);                  // 40,960 (adjacent to counts)
    int*   colsS   = (int*)(ws + 23748608);                  // 640,000
    float* valsS   = (float*)(ws + 24388608);                // 640,000  -> total ~25.0 MB

    // --- prep ---
    zero_int<<<(20480 + 255) / 256, 256, 0, stream>>>(counts, 20480);  // counts + fill
    cvt_f32_bf16<<<(NNODES * H / 4 + 255) / 256, 256, 0, stream>>>(feat, x, NNODES * H / 4);
    dim3 tb(32, 8), tg(16, 16);
    for (int l = 0; l < NLAYERS; ++l)
        transpose_cvt<<<tg, tb, 0, stream>>>(Wg + (size_t)l * H * H, Wt + (size_t)l * H * H);
    transpose_cvt<<<tg, tb, 0, stream>>>(vw1, Wt + (size_t)NLAYERS * H * H);
    edge_hist<<<(NEDGES + 255) / 256, 256, 0, stream>>>(adj_row, counts, NEDGES);
    scan_rows<<<1, 1024, 0, stream>>>(counts, row_ptr, NNODES);
    edge_scatter<<<(NEDGES + 255) / 256, 256, 0, stream>>>(adj_row, adj_col, adj_val,
                                                           row_ptr, fill, colsS, valsS, NEDGES);

    // --- layers ---
    dim3 gg((NNODES + 127) / 128, H / 128);
    for (int l = 0; l < NLAYERS; ++l) {
        gemm_bf16_bt<<<gg, 256, 0, stream>>>(x, Wt + (size_t)l * H * H, h, nullptr, 0, NNODES, H, H);
        spmm_bias_relu<<<NNODES, H, 0, stream>>>(row_ptr, colsS, valsS, h, bg + (size_t)l * H, x);
    }
    gemm_bf16_bt<<<gg, 256, 0, stream>>>(x, Wt + (size_t)NLAYERS * H * H, h, vb1, 1, NNODES, H, H);
    final_head<<<(NNODES + 3) / 4, 256, 0, stream>>>(h, vw2, vb2, out, NNODES);
}

// Round 2
// 372.034 us; speedup vs baseline: 1.6036x; 1.6036x over previous
//
#include <hip/hip_runtime.h>

#define H 512
#define NNODES 10000
#define NEDGES 160000
#define NLAYERS 5

typedef __attribute__((ext_vector_type(8))) short short8;
typedef __attribute__((ext_vector_type(4))) float floatx4;

// ---------- helpers ----------
__device__ inline unsigned short f2bf(float v) {
    union { float f; unsigned int u; } x; x.f = v;
    unsigned int r = (x.u + 0x7fffu + ((x.u >> 16) & 1u)) >> 16;
    return (unsigned short)r;
}
__device__ inline float bf2f(unsigned short u) {
    union { unsigned int u; float f; } x; x.u = ((unsigned int)u) << 16; return x.f;
}
__device__ inline void gl_lds16(const void* g, void* l) {
    __builtin_amdgcn_global_load_lds((const __attribute__((address_space(1))) void*)g,
                                     (__attribute__((address_space(3))) void*)l, 16, 0, 0);
}

// ---------- prep kernels ----------
__global__ void zero_int(int* __restrict__ p, int n) {
    int i = blockIdx.x * blockDim.x + threadIdx.x;
    if (i < n) p[i] = 0;
}

__global__ void cvt_f32_bf16(const float* __restrict__ in, unsigned short* __restrict__ out, int n4) {
    int i = blockIdx.x * blockDim.x + threadIdx.x;
    if (i < n4) {
        float4 v = ((const float4*)in)[i];
        ushort4 o;
        o.x = f2bf(v.x); o.y = f2bf(v.y); o.z = f2bf(v.z); o.w = f2bf(v.w);
        ((ushort4*)out)[i] = o;
    }
}

// in: [512][512] fp32 (K-major), out: [512][512] bf16 with out[n][k] = in[k][n]
__global__ void transpose_cvt(const float* __restrict__ in, unsigned short* __restrict__ out) {
    __shared__ float tile[32][33];
    const int bx = blockIdx.x * 32;  // n base
    const int by = blockIdx.y * 32;  // k base
    const int tx = threadIdx.x, ty = threadIdx.y;  // (32,8)
    for (int i = ty; i < 32; i += 8)
        tile[i][tx] = in[(size_t)(by + i) * H + bx + tx];
    __syncthreads();
    for (int i = ty; i < 32; i += 8)
        out[(size_t)(bx + i) * H + by + tx] = f2bf(tile[tx][i]);
}

__global__ void edge_hist(const int* __restrict__ rows, int* __restrict__ counts, int n) {
    int i = blockIdx.x * blockDim.x + threadIdx.x;
    if (i < n) atomicAdd(&counts[rows[i]], 1);
}

__global__ __launch_bounds__(1024)
void scan_rows(const int* __restrict__ counts, int* __restrict__ row_ptr, int n) {
    __shared__ int sums[1024];
    const int t = threadIdx.x;
    const int base = t * 16;
    int local[16];
    int s = 0;
#pragma unroll
    for (int i = 0; i < 16; ++i) {
        int idx = base + i;
        int v = (idx < n) ? counts[idx] : 0;
        local[i] = s;
        s += v;
    }
    sums[t] = s;
    __syncthreads();
    for (int off = 1; off < 1024; off <<= 1) {
        int v = (t >= off) ? sums[t - off] : 0;
        __syncthreads();
        sums[t] += v;
        __syncthreads();
    }
    const int prefix = (t == 0) ? 0 : sums[t - 1];
#pragma unroll
    for (int i = 0; i < 16; ++i) {
        int idx = base + i;
        if (idx < n) row_ptr[idx] = prefix + local[i];
    }
    if (t == 0) row_ptr[n] = sums[1023];
}

__global__ void edge_scatter(const int* __restrict__ rows, const int* __restrict__ colsin,
                             const float* __restrict__ valsin, const int* __restrict__ row_ptr,
                             int* __restrict__ fill, int* __restrict__ colsout,
                             float* __restrict__ valsout, int n) {
    int i = blockIdx.x * blockDim.x + threadIdx.x;
    if (i < n) {
        int r = rows[i];
        int pos = row_ptr[r] + atomicAdd(&fill[r], 1);
        colsout[pos] = colsin[i];
        valsout[pos] = valsin[i];
    }
}

// ---------- GEMM: C[M,N](bf16) = A[M,K](bf16) * Bt[N,K](bf16)^T, opt bias+relu ----------
__global__ __launch_bounds__(256)
void gemm_bf16_bt(const unsigned short* __restrict__ A, const unsigned short* __restrict__ Bt,
                  unsigned short* __restrict__ C, const float* __restrict__ bias,
                  int has_bias_relu, int M, int N, int K) {
    __shared__ __align__(16) unsigned short lsA[128 * 32];
    __shared__ __align__(16) unsigned short lsB[128 * 32];
    const int t = threadIdx.x;
    const int lane = t & 63;
    const int wave = t >> 6;
    const int wm = wave >> 1, wn = wave & 1;
    const int tileM = blockIdx.x * 128;
    const int tileN = blockIdx.y * 128;
    const int quad = lane >> 4, r16 = lane & 15;

    floatx4 acc[4][4] = {};

    const int c0 = t, c1 = t + 256;
    const int arow0 = c0 >> 2, akc0 = c0 & 3;
    const int arow1 = c1 >> 2, akc1 = c1 & 3;
    int agr0 = tileM + arow0; if (agr0 >= M) agr0 = M - 1;
    int agr1 = tileM + arow1; if (agr1 >= M) agr1 = M - 1;
    const int bgr0 = tileN + arow0;
    const int bgr1 = tileN + arow1;

    for (int k0 = 0; k0 < K; k0 += 32) {
        gl_lds16(A + (size_t)agr0 * K + k0 + akc0 * 8, lsA + c0 * 8);
        gl_lds16(A + (size_t)agr1 * K + k0 + akc1 * 8, lsA + c1 * 8);
        gl_lds16(Bt + (size_t)bgr0 * K + k0 + akc0 * 8, lsB + c0 * 8);
        gl_lds16(Bt + (size_t)bgr1 * K + k0 + akc1 * 8, lsB + c1 * 8);
        __syncthreads();

        short8 af[4], bf[4];
#pragma unroll
        for (int i = 0; i < 4; ++i)
            af[i] = *(const short8*)&lsA[(wm * 64 + i * 16 + r16) * 32 + quad * 8];
#pragma unroll
        for (int j = 0; j < 4; ++j)
            bf[j] = *(const short8*)&lsB[(wn * 64 + j * 16 + r16) * 32 + quad * 8];
#pragma unroll
        for (int i = 0; i < 4; ++i)
#pragma unroll
            for (int j = 0; j < 4; ++j)
                acc[i][j] = __builtin_amdgcn_mfma_f32_16x16x32_bf16(af[i], bf[j], acc[i][j], 0, 0, 0);
        __syncthreads();
    }

#pragma unroll
    for (int i = 0; i < 4; ++i) {
#pragma unroll
        for (int j = 0; j < 4; ++j) {
            const int col = tileN + wn * 64 + j * 16 + r16;
#pragma unroll
            for (int reg = 0; reg < 4; ++reg) {
                const int row = tileM + wm * 64 + i * 16 + quad * 4 + reg;
                if (row < M) {
                    float v = acc[i][j][reg];
                    if (has_bias_relu) { v += bias[col]; v = fmaxf(v, 0.f); }
                    C[(size_t)row * N + col] = f2bf(v);
                }
            }
        }
    }
}

// ---------- SpMM + bias + relu: one WAVE per row, 16B/lane gathers, 4-deep unroll ----------
__global__ __launch_bounds__(256)
void spmm_bias_relu(const int* __restrict__ row_ptr, const int* __restrict__ cols,
                    const float* __restrict__ vals, const unsigned short* __restrict__ hmat,
                    const float* __restrict__ bias, unsigned short* __restrict__ xout) {
    const int wave = threadIdx.x >> 6, lane = threadIdx.x & 63;
    const int r = blockIdx.x * 4 + wave;
    if (r >= NNODES) return;
    const int s = row_ptr[r], e = row_ptr[r + 1];
    const int cb = lane * 8;  // this lane's 8 contiguous columns
    float acc[8] = {0.f, 0.f, 0.f, 0.f, 0.f, 0.f, 0.f, 0.f};

    int i = s;
    for (; i + 4 <= e; i += 4) {
        const int c0 = cols[i + 0], c1 = cols[i + 1], c2 = cols[i + 2], c3 = cols[i + 3];
        const float v0 = vals[i + 0], v1 = vals[i + 1], v2 = vals[i + 2], v3 = vals[i + 3];
        // 4 independent 16B gathers in flight
        short8 g0 = *(const short8*)(hmat + (size_t)c0 * H + cb);
        short8 g1 = *(const short8*)(hmat + (size_t)c1 * H + cb);
        short8 g2 = *(const short8*)(hmat + (size_t)c2 * H + cb);
        short8 g3 = *(const short8*)(hmat + (size_t)c3 * H + cb);
#pragma unroll
        for (int j = 0; j < 8; ++j) {
            // per-column accumulation order == edge order (bit-identical to r1)
            acc[j] += v0 * bf2f((unsigned short)g0[j]);
            acc[j] += v1 * bf2f((unsigned short)g1[j]);
            acc[j] += v2 * bf2f((unsigned short)g2[j]);
            acc[j] += v3 * bf2f((unsigned short)g3[j]);
        }
    }
    for (; i < e; ++i) {
        const int c = cols[i];
        const float v = vals[i];
        short8 g = *(const short8*)(hmat + (size_t)c * H + cb);
#pragma unroll
        for (int j = 0; j < 8; ++j) acc[j] += v * bf2f((unsigned short)g[j]);
    }

    short8 o;
#pragma unroll
    for (int j = 0; j < 8; ++j)
        o[j] = (short)f2bf(fmaxf(acc[j] + bias[cb + j], 0.f));
    *(short8*)(xout + (size_t)r * H + cb) = o;
}

// ---------- head: out[r] = sigmoid(dot(h2[r,:], w2) + b2) ----------
__global__ __launch_bounds__(256)
void final_head(const unsigned short* __restrict__ h2, const float* __restrict__ w2,
                const float* __restrict__ b2, float* __restrict__ out, int n) {
    const int wave = threadIdx.x >> 6, lane = threadIdx.x & 63;
    const int r = blockIdx.x * 4 + wave;
    if (r >= n) return;
    const unsigned short* hrow = h2 + (size_t)r * H;
    float acc = 0.f;
#pragma unroll
    for (int i = 0; i < 8; ++i) {
        const int c = lane * 8 + i;
        acc += bf2f(hrow[c]) * w2[c];
    }
#pragma unroll
    for (int off = 32; off >= 1; off >>= 1) acc += __shfl_xor(acc, off, 64);
    if (lane == 0) out[r] = 1.f / (1.f + expf(-(acc + b2[0])));
}

extern "C" void kernel_launch(void* const* d_in, const int* in_sizes, int n_in,
                              void* d_out, int out_size, void* d_ws, size_t ws_size,
                              hipStream_t stream) {
    (void)in_sizes; (void)n_in; (void)out_size; (void)ws_size;
    const float* feat   = (const float*)d_in[0];
    const int* adj_row  = (const int*)d_in[1];
    const int* adj_col  = (const int*)d_in[2];
    const float* adj_val= (const float*)d_in[3];
    const float* Wg     = (const float*)d_in[4];
    const float* bg     = (const float*)d_in[5];
    const float* vw1    = (const float*)d_in[6];
    const float* vb1    = (const float*)d_in[7];
    const float* vw2    = (const float*)d_in[8];
    const float* vb2    = (const float*)d_in[9];
    float* out = (float*)d_out;

    // workspace layout (bytes)
    char* ws = (char*)d_ws;
    unsigned short* x  = (unsigned short*)(ws + 0);          // 10,240,000
    unsigned short* h  = (unsigned short*)(ws + 10240000);   // 10,240,000
    unsigned short* Wt = (unsigned short*)(ws + 20480000);   // 3,145,728
    int*   row_ptr = (int*)(ws + 23625728);                  // 40,960
    int*   counts  = (int*)(ws + 23666688);                  // 40,960
    int*   fill    = (int*)(ws + 23707648);                  // 40,960
    int*   colsS   = (int*)(ws + 23748608);                  // 640,000
    float* valsS   = (float*)(ws + 24388608);                // 640,000  -> total ~25.0 MB

    // --- prep ---
    zero_int<<<(20480 + 255) / 256, 256, 0, stream>>>(counts, 20480);  // counts + fill
    cvt_f32_bf16<<<(NNODES * H / 4 + 255) / 256, 256, 0, stream>>>(feat, x, NNODES * H / 4);
    dim3 tb(32, 8), tg(16, 16);
    for (int l = 0; l < NLAYERS; ++l)
        transpose_cvt<<<tg, tb, 0, stream>>>(Wg + (size_t)l * H * H, Wt + (size_t)l * H * H);
    transpose_cvt<<<tg, tb, 0, stream>>>(vw1, Wt + (size_t)NLAYERS * H * H);
    edge_hist<<<(NEDGES + 255) / 256, 256, 0, stream>>>(adj_row, counts, NEDGES);
    scan_rows<<<1, 1024, 0, stream>>>(counts, row_ptr, NNODES);
    edge_scatter<<<(NEDGES + 255) / 256, 256, 0, stream>>>(adj_row, adj_col, adj_val,
                                                           row_ptr, fill, colsS, valsS, NEDGES);

    // --- layers ---
    dim3 gg((NNODES + 127) / 128, H / 128);
    for (int l = 0; l < NLAYERS; ++l) {
        gemm_bf16_bt<<<gg, 256, 0, stream>>>(x, Wt + (size_t)l * H * H, h, nullptr, 0, NNODES, H, H);
        spmm_bias_relu<<<(NNODES + 3) / 4, 256, 0, stream>>>(row_ptr, colsS, valsS, h, bg + (size_t)l * H, x);
    }
    gemm_bf16_bt<<<gg, 256, 0, stream>>>(x, Wt + (size_t)NLAYERS * H * H, h, vb1, 1, NNODES, H, H);
    final_head<<<(NNODES + 3) / 4, 256, 0, stream>>>(h, vw2, vb2, out, NNODES);
}

// Round 3
// 366.886 us; speedup vs baseline: 1.6261x; 1.0140x over previous
//
#include <hip/hip_runtime.h>

#define H 512
#define NNODES 10000
#define NEDGES 160000
#define NLAYERS 5

typedef __attribute__((ext_vector_type(8))) short short8;
typedef __attribute__((ext_vector_type(4))) float floatx4;

// ---------- helpers ----------
__device__ inline unsigned short f2bf(float v) {
    union { float f; unsigned int u; } x; x.f = v;
    unsigned int r = (x.u + 0x7fffu + ((x.u >> 16) & 1u)) >> 16;
    return (unsigned short)r;
}
__device__ inline float bf2f(unsigned short u) {
    union { unsigned int u; float f; } x; x.u = ((unsigned int)u) << 16; return x.f;
}
__device__ inline void gl_lds16(const void* g, void* l) {
    __builtin_amdgcn_global_load_lds((const __attribute__((address_space(1))) void*)g,
                                     (__attribute__((address_space(3))) void*)l, 16, 0, 0);
}

// ---------- prep kernels ----------
__global__ void zero_int(int* __restrict__ p, int n) {
    int i = blockIdx.x * blockDim.x + threadIdx.x;
    if (i < n) p[i] = 0;
}

__global__ void cvt_f32_bf16(const float* __restrict__ in, unsigned short* __restrict__ out, int n4) {
    int i = blockIdx.x * blockDim.x + threadIdx.x;
    if (i < n4) {
        float4 v = ((const float4*)in)[i];
        ushort4 o;
        o.x = f2bf(v.x); o.y = f2bf(v.y); o.z = f2bf(v.z); o.w = f2bf(v.w);
        ((ushort4*)out)[i] = o;
    }
}

// batched: z in [0,6): 5 layer weights + vw1. out[n][k] = in[k][n], bf16
__global__ void transpose_cvt6(const float* __restrict__ Wg, const float* __restrict__ vw1,
                               unsigned short* __restrict__ Wt) {
    __shared__ float tile[32][33];
    const int z = blockIdx.z;
    const float* in = (z < NLAYERS) ? (Wg + (size_t)z * H * H) : vw1;
    unsigned short* out = Wt + (size_t)z * H * H;
    const int bx = blockIdx.x * 32;  // n base
    const int by = blockIdx.y * 32;  // k base
    const int tx = threadIdx.x, ty = threadIdx.y;  // (32,8)
    for (int i = ty; i < 32; i += 8)
        tile[i][tx] = in[(size_t)(by + i) * H + bx + tx];
    __syncthreads();
    for (int i = ty; i < 32; i += 8)
        out[(size_t)(bx + i) * H + by + tx] = f2bf(tile[tx][i]);
}

__global__ void edge_hist(const int* __restrict__ rows, int* __restrict__ counts, int n) {
    int i = blockIdx.x * blockDim.x + threadIdx.x;
    if (i < n) atomicAdd(&counts[rows[i]], 1);
}

__global__ __launch_bounds__(1024)
void scan_rows(const int* __restrict__ counts, int* __restrict__ row_ptr, int n) {
    __shared__ int sums[1024];
    const int t = threadIdx.x;
    const int base = t * 16;
    int local[16];
    int s = 0;
#pragma unroll
    for (int i = 0; i < 16; ++i) {
        int idx = base + i;
        int v = (idx < n) ? counts[idx] : 0;
        local[i] = s;
        s += v;
    }
    sums[t] = s;
    __syncthreads();
    for (int off = 1; off < 1024; off <<= 1) {
        int v = (t >= off) ? sums[t - off] : 0;
        __syncthreads();
        sums[t] += v;
        __syncthreads();
    }
    const int prefix = (t == 0) ? 0 : sums[t - 1];
#pragma unroll
    for (int i = 0; i < 16; ++i) {
        int idx = base + i;
        if (idx < n) row_ptr[idx] = prefix + local[i];
    }
    if (t == 0) row_ptr[n] = sums[1023];
}

__global__ void edge_scatter(const int* __restrict__ rows, const int* __restrict__ colsin,
                             const float* __restrict__ valsin, const int* __restrict__ row_ptr,
                             int* __restrict__ fill, int* __restrict__ colsout,
                             float* __restrict__ valsout, int* __restrict__ eidx, int n) {
    int i = blockIdx.x * blockDim.x + threadIdx.x;
    if (i < n) {
        int r = rows[i];
        int pos = row_ptr[r] + atomicAdd(&fill[r], 1);
        colsout[pos] = colsin[i];
        valsout[pos] = valsin[i];
        eidx[pos] = i;
    }
}

// per-row odd-even transposition sort by original edge index -> accumulation
// order matches reference segment_sum exactly (deterministic absmax).
__global__ __launch_bounds__(256)
void sort_rows(const int* __restrict__ row_ptr, int* __restrict__ cols,
               float* __restrict__ vals, const int* __restrict__ eidx) {
    const int wave = threadIdx.x >> 6, lane = threadIdx.x & 63;
    const int r = blockIdx.x * 4 + wave;
    if (r >= NNODES) return;
    const int s = row_ptr[r], e = row_ptr[r + 1];
    const int len = e - s;
    if (len <= 1) return;
    const int n = len < 64 ? len : 64;
    int key = (lane < n) ? eidx[s + lane] : 0x7fffffff;
    int col = (lane < n) ? cols[s + lane] : 0;
    float val = (lane < n) ? vals[s + lane] : 0.f;
    for (int rd = 0; rd < 64; ++rd) {
        const int p = rd & 1;
        const bool up = ((lane & 1) == p);
        int partner = up ? lane + 1 : lane - 1;
        const bool valid = (partner >= 0) && (partner < 64);
        if (!valid) partner = lane;
        int pk = __shfl(key, partner, 64);
        int pc = __shfl(col, partner, 64);
        float pv = __shfl(val, partner, 64);
        if (valid) {
            const bool sw = up ? (pk < key) : (pk > key);
            if (sw) { key = pk; col = pc; val = pv; }
        }
    }
    if (lane < n) { cols[s + lane] = col; vals[s + lane] = val; }
}

// ---------- GEMM: C[M,512](bf16) = A[M,512](bf16) * Bt[512,512](bf16)^T ----------
// TM=128, TN=64, BK=64, grid (ceil(M/128), 8) = 632 blocks (2.47/CU balance).
// XOR-swizzled LDS K-chunk slots -> conflict-free ds_read_b128.
__global__ __launch_bounds__(256)
void gemm_bf16_bt(const unsigned short* __restrict__ A, const unsigned short* __restrict__ Bt,
                  unsigned short* __restrict__ C, const float* __restrict__ bias,
                  int has_bias_relu, int M) {
    __shared__ __align__(16) unsigned short lsA[128 * 64];  // 16 KB
    __shared__ __align__(16) unsigned short lsB[64 * 64];   //  8 KB
    const int t = threadIdx.x;
    const int lane = t & 63;
    const int wave = t >> 6;
    const int wm = wave >> 1, wn = wave & 1;
    const int tileM = blockIdx.x * 128;
    const int tileN = blockIdx.y * 64;
    const int quad = lane >> 4, r16 = lane & 15;

    floatx4 acc[4][2] = {};

    // A staging: 1024 slots of 16B; slot s holds global chunk (row=s>>3, kc=(s&7)^(row&7))
    const unsigned short* ap[4];
#pragma unroll
    for (int q = 0; q < 4; ++q) {
        const int c = t + 256 * q;
        const int row = c >> 3;
        int g = tileM + row; if (g >= M) g = M - 1;
        ap[q] = A + (size_t)g * 512 + (((c & 7) ^ (row & 7)) * 8);
    }
    // B staging: 512 slots
    const unsigned short* bp[2];
#pragma unroll
    for (int q = 0; q < 2; ++q) {
        const int c = t + 256 * q;
        const int row = c >> 3;
        bp[q] = Bt + (size_t)(tileN + row) * 512 + (((c & 7) ^ (row & 7)) * 8);
    }

    for (int k0 = 0; k0 < 512; k0 += 64) {
        gl_lds16(ap[0] + k0, lsA + (size_t)t * 8);
        gl_lds16(ap[1] + k0, lsA + (size_t)(t + 256) * 8);
        gl_lds16(ap[2] + k0, lsA + (size_t)(t + 512) * 8);
        gl_lds16(ap[3] + k0, lsA + (size_t)(t + 768) * 8);
        gl_lds16(bp[0] + k0, lsB + (size_t)t * 8);
        gl_lds16(bp[1] + k0, lsB + (size_t)(t + 256) * 8);
        __syncthreads();

        short8 af[4][2], bfr[2][2];
#pragma unroll
        for (int i = 0; i < 4; ++i) {
            const int row = wm * 64 + i * 16 + r16;
#pragma unroll
            for (int kk = 0; kk < 2; ++kk) {
                const int kcw = kk * 4 + quad;
                af[i][kk] = *(const short8*)&lsA[(size_t)(row * 8 + (kcw ^ (row & 7))) * 8];
            }
        }
#pragma unroll
        for (int j = 0; j < 2; ++j) {
            const int row = wn * 32 + j * 16 + r16;
#pragma unroll
            for (int kk = 0; kk < 2; ++kk) {
                const int kcw = kk * 4 + quad;
                bfr[j][kk] = *(const short8*)&lsB[(size_t)(row * 8 + (kcw ^ (row & 7))) * 8];
            }
        }
#pragma unroll
        for (int kk = 0; kk < 2; ++kk)  // K ascending: numerics identical to BK=32 version
#pragma unroll
            for (int i = 0; i < 4; ++i)
#pragma unroll
                for (int j = 0; j < 2; ++j)
                    acc[i][j] = __builtin_amdgcn_mfma_f32_16x16x32_bf16(af[i][kk], bfr[j][kk], acc[i][j], 0, 0, 0);
        __syncthreads();
    }

    // epilogue: C/D map col=lane&15, row=(lane>>4)*4+reg
#pragma unroll
    for (int i = 0; i < 4; ++i) {
#pragma unroll
        for (int j = 0; j < 2; ++j) {
            const int col = tileN + wn * 32 + j * 16 + r16;
#pragma unroll
            for (int reg = 0; reg < 4; ++reg) {
                const int row = tileM + wm * 64 + i * 16 + quad * 4 + reg;
                if (row < M) {
                    float v = acc[i][j][reg];
                    if (has_bias_relu) { v += bias[col]; v = fmaxf(v, 0.f); }
                    C[(size_t)row * 512 + col] = f2bf(v);
                }
            }
        }
    }
}

// ---------- SpMM + bias + relu: one wave/row, 16B/lane gathers, 8-deep unroll ----------
__global__ __launch_bounds__(256)
void spmm_bias_relu(const int* __restrict__ row_ptr, const int* __restrict__ cols,
                    const float* __restrict__ vals, const unsigned short* __restrict__ hmat,
                    const float* __restrict__ bias, unsigned short* __restrict__ xout) {
    const int wave = threadIdx.x >> 6, lane = threadIdx.x & 63;
    const int r = blockIdx.x * 4 + wave;
    if (r >= NNODES) return;
    const int s = row_ptr[r], e = row_ptr[r + 1];
    const int cb = lane * 8;
    float acc[8] = {0.f, 0.f, 0.f, 0.f, 0.f, 0.f, 0.f, 0.f};

    int i = s;
    for (; i + 8 <= e; i += 8) {
        int c[8]; float v[8]; short8 g[8];
#pragma unroll
        for (int u = 0; u < 8; ++u) { c[u] = cols[i + u]; v[u] = vals[i + u]; }
#pragma unroll
        for (int u = 0; u < 8; ++u) g[u] = *(const short8*)(hmat + (size_t)c[u] * H + cb);
#pragma unroll
        for (int u = 0; u < 8; ++u)  // edge order preserved per column
#pragma unroll
            for (int j = 0; j < 8; ++j) acc[j] += v[u] * bf2f((unsigned short)g[u][j]);
    }
    for (; i + 2 <= e; i += 2) {
        const int c0 = cols[i], c1 = cols[i + 1];
        const float v0 = vals[i], v1 = vals[i + 1];
        short8 g0 = *(const short8*)(hmat + (size_t)c0 * H + cb);
        short8 g1 = *(const short8*)(hmat + (size_t)c1 * H + cb);
#pragma unroll
        for (int j = 0; j < 8; ++j) { acc[j] += v0 * bf2f((unsigned short)g0[j]); }
#pragma unroll
        for (int j = 0; j < 8; ++j) { acc[j] += v1 * bf2f((unsigned short)g1[j]); }
    }
    if (i < e) {
        const int c = cols[i];
        const float v = vals[i];
        short8 g = *(const short8*)(hmat + (size_t)c * H + cb);
#pragma unroll
        for (int j = 0; j < 8; ++j) acc[j] += v * bf2f((unsigned short)g[j]);
    }

    short8 o;
#pragma unroll
    for (int j = 0; j < 8; ++j)
        o[j] = (short)f2bf(fmaxf(acc[j] + bias[cb + j], 0.f));
    *(short8*)(xout + (size_t)r * H + cb) = o;
}

// ---------- head: out[r] = sigmoid(dot(h2[r,:], w2) + b2) ----------
__global__ __launch_bounds__(256)
void final_head(const unsigned short* __restrict__ h2, const float* __restrict__ w2,
                const float* __restrict__ b2, float* __restrict__ out, int n) {
    const int wave = threadIdx.x >> 6, lane = threadIdx.x & 63;
    const int r = blockIdx.x * 4 + wave;
    if (r >= n) return;
    const unsigned short* hrow = h2 + (size_t)r * H;
    float acc = 0.f;
#pragma unroll
    for (int i = 0; i < 8; ++i) {
        const int c = lane * 8 + i;
        acc += bf2f(hrow[c]) * w2[c];
    }
#pragma unroll
    for (int off = 32; off >= 1; off >>= 1) acc += __shfl_xor(acc, off, 64);
    if (lane == 0) out[r] = 1.f / (1.f + expf(-(acc + b2[0])));
}

extern "C" void kernel_launch(void* const* d_in, const int* in_sizes, int n_in,
                              void* d_out, int out_size, void* d_ws, size_t ws_size,
                              hipStream_t stream) {
    (void)in_sizes; (void)n_in; (void)out_size; (void)ws_size;
    const float* feat   = (const float*)d_in[0];
    const int* adj_row  = (const int*)d_in[1];
    const int* adj_col  = (const int*)d_in[2];
    const float* adj_val= (const float*)d_in[3];
    const float* Wg     = (const float*)d_in[4];
    const float* bg     = (const float*)d_in[5];
    const float* vw1    = (const float*)d_in[6];
    const float* vb1    = (const float*)d_in[7];
    const float* vw2    = (const float*)d_in[8];
    const float* vb2    = (const float*)d_in[9];
    float* out = (float*)d_out;

    // workspace layout (bytes)
    char* ws = (char*)d_ws;
    unsigned short* x  = (unsigned short*)(ws + 0);          // 10,240,000
    unsigned short* h  = (unsigned short*)(ws + 10240000);   // 10,240,000
    unsigned short* Wt = (unsigned short*)(ws + 20480000);   // 3,145,728
    int*   row_ptr = (int*)(ws + 23625728);                  // 40,960
    int*   counts  = (int*)(ws + 23666688);                  // 40,960
    int*   fill    = (int*)(ws + 23707648);                  // 40,960
    int*   colsS   = (int*)(ws + 23748608);                  // 640,000
    float* valsS   = (float*)(ws + 24388608);                // 640,000
    int*   eidxS   = (int*)(ws + 25028608);                  // 640,000 -> ~25.7 MB

    // --- prep ---
    zero_int<<<(20480 + 255) / 256, 256, 0, stream>>>(counts, 20480);  // counts + fill
    cvt_f32_bf16<<<(NNODES * H / 4 + 255) / 256, 256, 0, stream>>>(feat, x, NNODES * H / 4);
    transpose_cvt6<<<dim3(16, 16, 6), dim3(32, 8), 0, stream>>>(Wg, vw1, Wt);
    edge_hist<<<(NEDGES + 255) / 256, 256, 0, stream>>>(adj_row, counts, NEDGES);
    scan_rows<<<1, 1024, 0, stream>>>(counts, row_ptr, NNODES);
    edge_scatter<<<(NEDGES + 255) / 256, 256, 0, stream>>>(adj_row, adj_col, adj_val,
                                                           row_ptr, fill, colsS, valsS, eidxS, NEDGES);
    sort_rows<<<(NNODES + 3) / 4, 256, 0, stream>>>(row_ptr, colsS, valsS, eidxS);

    // --- layers ---
    dim3 gg((NNODES + 127) / 128, 8);
    for (int l = 0; l < NLAYERS; ++l) {
        gemm_bf16_bt<<<gg, 256, 0, stream>>>(x, Wt + (size_t)l * H * H, h, nullptr, 0, NNODES);
        spmm_bias_relu<<<(NNODES + 3) / 4, 256, 0, stream>>>(row_ptr, colsS, valsS, h, bg + (size_t)l * H, x);
    }
    gemm_bf16_bt<<<gg, 256, 0, stream>>>(x, Wt + (size_t)NLAYERS * H * H, h, vb1, 1, NNODES);
    final_head<<<(NNODES + 3) / 4, 256, 0, stream>>>(h, vw2, vb2, out, NNODES);
}